// Round 1
// baseline (1255.659 us; speedup 1.0000x reference)
//
#include <hip/hip_runtime.h>
#include <hip/hip_bf16.h>

// B=8 S=256 H=768 D=128 L=64, all inputs f32.
// Outputs: relate_score (8*64) | lm_b (8*64*128) | lc_b (8*64*128*128), f32.

#define TRI(i,j) ((((i)*((i)+1))>>1) + (j))

// ---------------------------------------------------------------- K1: wm/wv GEMM
// grid (128, 2), block 256. Tile: 16 rows x 128 cols, K-chunks of 64.
__global__ __launch_bounds__(256, 2)
void k1_gemm(const float* __restrict__ Am, const float* __restrict__ Av,
             const float* __restrict__ W1, const float* __restrict__ B1,
             const float* __restrict__ W2, const float* __restrict__ B2,
             float* __restrict__ wm, float* __restrict__ wv) {
    __shared__ float At[16][64];
    __shared__ __align__(16) float Wt[64][128];
    const int tid = threadIdx.x;
    const int sel = blockIdx.y;
    const float* A = sel ? Av : Am;
    const float* W = sel ? W2 : W1;
    const float* Bs = sel ? B2 : B1;
    float* D = sel ? wv : wm;
    const int R0 = blockIdx.x * 16;
    const int r = tid >> 4;
    const int j0 = (tid & 15) * 8;
    float acc[8] = {0.f,0.f,0.f,0.f,0.f,0.f,0.f,0.f};
    for (int k0 = 0; k0 < 768; k0 += 64) {
        __syncthreads();
#pragma unroll
        for (int it = 0; it < 4; ++it) {
            int f = tid + it * 256;
            int rr = f >> 6, cc = f & 63;
            At[rr][cc] = A[(size_t)(R0 + rr) * 768 + k0 + cc];
        }
#pragma unroll
        for (int it = 0; it < 8; ++it) {
            int f = tid + it * 256;            // float4 index into 64x128 tile
            int rr = f >> 5, c4 = (f & 31) * 4;
            *(float4*)&Wt[rr][c4] = *(const float4*)&W[(size_t)(k0 + rr) * 128 + c4];
        }
        __syncthreads();
#pragma unroll 8
        for (int kk = 0; kk < 64; ++kk) {
            float a = At[r][kk];
            float4 w0 = *(const float4*)&Wt[kk][j0];
            float4 w1 = *(const float4*)&Wt[kk][j0 + 4];
            acc[0] += a * w0.x; acc[1] += a * w0.y; acc[2] += a * w0.z; acc[3] += a * w0.w;
            acc[4] += a * w1.x; acc[5] += a * w1.y; acc[6] += a * w1.z; acc[7] += a * w1.w;
        }
    }
    size_t ob = (size_t)(R0 + r) * 128 + j0;
#pragma unroll
    for (int c = 0; c < 8; ++c) D[ob + c] = acc[c] + Bs[j0 + c];
}

// ---------------------------------------------------------------- K1b: sm/sv
__global__ __launch_bounds__(128)
void k1b_sent(const float* __restrict__ sfm, const float* __restrict__ sfd,
              const float* __restrict__ W3, const float* __restrict__ B3,
              const float* __restrict__ W4, const float* __restrict__ B4,
              float* __restrict__ sm, float* __restrict__ sv) {
    int b = blockIdx.x, d = threadIdx.x;
    const float* m = sfm + (size_t)b * 768;
    const float* v = sfd + (size_t)b * 768;
    float am = 0.f, av = 0.f;
    for (int h = 0; h < 768; ++h) {
        float fm = m[h], fv = v[h];
        am += fm * W3[(size_t)h * 128 + d];
        av += fv * W4[(size_t)h * 128 + d];
    }
    sm[b * 128 + d] = am + B3[d];
    sv[b * 128 + d] = av + B4[d];
}

// ---------------------------------------------------------------- K2a: per-row scalars
// rows 0..2047: (b,s) over wm/wv;  rows 2048..2111: labels. One wave per row.
__global__ __launch_bounds__(256)
void k2a_scal(const float* __restrict__ wm, const float* __restrict__ wv,
              const float* __restrict__ lm, const float* __restrict__ ldv,
              float4* __restrict__ rowsc, float4* __restrict__ labsc) {
    int row = blockIdx.x * 4 + (threadIdx.x >> 6);
    int lane = threadIdx.x & 63;
    const float *pm, *pv;
    bool isLab;
    int l = 0;
    if (row < 2048) {
        pm = wm + (size_t)row * 128; pv = wv + (size_t)row * 128; isLab = false;
    } else if (row < 2112) {
        l = row - 2048;
        pm = lm + (size_t)l * 128; pv = ldv + (size_t)l * 128; isLab = true;
    } else return;
    float m0 = pm[lane], m1 = pm[lane + 64];
    float v0 = pv[lane], v1 = pv[lane + 64];
    float s_m = m0 * m0 + m1 * m1;
    float s_v = v0 * v0 + v1 * v1;
    float s_mv = m0 * v0 + m1 * v1;
#pragma unroll
    for (int o = 32; o; o >>= 1) {
        s_m += __shfl_xor(s_m, o);
        s_v += __shfl_xor(s_v, o);
        s_mv += __shfl_xor(s_mv, o);
    }
    if (lane == 0) {
        float4 r = make_float4(1.f + s_v, s_m, s_mv, 0.f);
        if (isLab) labsc[l] = r; else rowsc[row] = r;
    }
}

// ---------------------------------------------------------------- K2b: logits + softmax -> score
// grid 512 = (b,l), block 256 (thread = s).
__global__ __launch_bounds__(256, 2)
void k2b_score(const float* __restrict__ wm, const float* __restrict__ wv,
               const float* __restrict__ lm, const float* __restrict__ ldv,
               const float4* __restrict__ rowsc, const float4* __restrict__ labsc,
               float* __restrict__ score) {
    __shared__ float mu[128], vp[128];
    __shared__ float wmT[256][17], wvT[256][17];   // pad 17: avoids 32-way bank conflicts
    __shared__ float red[4];
    const int tid = threadIdx.x;
    const int b = blockIdx.x >> 6, l = blockIdx.x & 63;
    if (tid < 128) {
        mu[tid] = lm[l * 128 + tid];
        vp[tid] = ldv[l * 128 + tid];
    }
    float dot = 0.f, md = 0.f, pvv = 0.f, vq = 0.f;
    const float* wmr = wm + (size_t)(b * 256 + tid) * 128;
    const float* wvr = wv + (size_t)(b * 256 + tid) * 128;
    for (int d0 = 0; d0 < 128; d0 += 16) {
        __syncthreads();
#pragma unroll
        for (int q = 0; q < 4; ++q) {
            float4 xm = *(const float4*)&wmr[d0 + q * 4];
            float4 xv = *(const float4*)&wvr[d0 + q * 4];
            wmT[tid][q * 4 + 0] = xm.x; wmT[tid][q * 4 + 1] = xm.y;
            wmT[tid][q * 4 + 2] = xm.z; wmT[tid][q * 4 + 3] = xm.w;
            wvT[tid][q * 4 + 0] = xv.x; wvT[tid][q * 4 + 1] = xv.y;
            wvT[tid][q * 4 + 2] = xv.z; wvT[tid][q * 4 + 3] = xv.w;
        }
        __syncthreads();
#pragma unroll
        for (int dd = 0; dd < 16; ++dd) {
            float am = mu[d0 + dd], av = vp[d0 + dd];
            float xm = wmT[tid][dd], xv = wvT[tid][dd];
            md += am * xm; dot += av * xv; pvv += am * xv; vq += av * xm;
        }
    }
    float4 rs = rowsc[b * 256 + tid];
    float4 ls = labsc[l];
    float nq = rs.x, mmq = rs.y, vmq = rs.z;
    float np = ls.x, mmp = ls.y, vmp = ls.z;
    float d2 = mmq - 2.f * md + mmp;
    float vqd = vmq - pvv, vpd = vq - vmp;
    float inq = 1.f / nq, inp = 1.f / np;
    float maha_q = d2 - vqd * vqd * inq;
    float maha_p = d2 - vpd * vpd * inp;
    // logs cancel in 0.5*(kl_pq + kl_qp)
    float logit = 0.25f * ((np - 1.f) + (nq - 1.f)
                           - (nq - 1.f + dot * dot) * inq
                           - (np - 1.f + dot * dot) * inp
                           + maha_q + maha_p);
    // softmax over the 256 threads
    float mx = logit;
#pragma unroll
    for (int o = 32; o; o >>= 1) mx = fmaxf(mx, __shfl_xor(mx, o));
    if ((tid & 63) == 0) red[tid >> 6] = mx;
    __syncthreads();
    mx = fmaxf(fmaxf(red[0], red[1]), fmaxf(red[2], red[3]));
    float e = expf(logit - mx);
    float s = e;
#pragma unroll
    for (int o = 32; o; o >>= 1) s += __shfl_xor(s, o);
    __syncthreads();
    if ((tid & 63) == 0) red[tid >> 6] = s;
    __syncthreads();
    float tot = red[0] + red[1] + red[2] + red[3];
    score[(size_t)blockIdx.x * 256 + tid] = e / tot;
}

// ---------------------------------------------------------------- block reduce helper
__device__ __forceinline__ float bsum(float v, float* red) {
#pragma unroll
    for (int o = 32; o; o >>= 1) v += __shfl_xor(v, o);
    __syncthreads();
    if ((threadIdx.x & 63) == 0) red[threadIdx.x >> 6] = v;
    __syncthreads();
    return red[0] + red[1] + red[2] + red[3];
}

// ---------------------------------------------------------------- K4: fused Sigma build + Cholesky + solves
// grid 512 = (b,l), block 256.
__global__ __launch_bounds__(256, 2)
void k4_main(const float* __restrict__ wm, const float* __restrict__ wv,
             const float* __restrict__ smg, const float* __restrict__ svg,
             const float* __restrict__ lmg, const float* __restrict__ ldvg,
             const float* __restrict__ score, float* __restrict__ outR) {
    __shared__ float P[8256];                       // packed lower triangle, in-place Sigma -> L -> L^{-1}
    __shared__ __align__(16) float wvT[16][128];
    __shared__ __align__(16) float wmT[16][128];
    __shared__ float scoreL[256];
    __shared__ float svr[128], vrow[128], zv[128], zd[128];
    __shared__ float red[4];
    __shared__ float scal;
    const int tid = threadIdx.x;
    const int bid = blockIdx.x;
    const int b = bid >> 6, l = bid & 63;
    const float* wvb = wv + (size_t)b * 256 * 128;
    const float* wmb = wm + (size_t)b * 256 * 128;
    scoreL[tid] = score[(size_t)bid * 256 + tid];
    if (tid < 128) {
        svr[tid] = svg[b * 128 + tid];
        vrow[tid] = ldvg[l * 128 + tid];
    }
    const int tx = tid & 15, ty = tid >> 4;
    const int i0 = ty * 8, j0 = tx * 8;
    float acc[8][8];
#pragma unroll
    for (int r = 0; r < 8; ++r)
#pragma unroll
        for (int c = 0; c < 8; ++c) acc[r][c] = 0.f;
    float vm = 0.f;
    // phase 1: M = Wv^T diag(score) Wv (full 128x128 in 8x8 reg tiles) + v_mean
    for (int s0 = 0; s0 < 256; s0 += 16) {
        __syncthreads();
#pragma unroll
        for (int it = 0; it < 2; ++it) {
            int f = tid + it * 256;
            int rr = f >> 5, c4 = (f & 31) * 4;
            *(float4*)&wvT[rr][c4] = *(const float4*)&wvb[(size_t)(s0 + rr) * 128 + c4];
            *(float4*)&wmT[rr][c4] = *(const float4*)&wmb[(size_t)(s0 + rr) * 128 + c4];
        }
        __syncthreads();
#pragma unroll 2
        for (int sc = 0; sc < 16; ++sc) {
            float ss = scoreL[s0 + sc];
            const float* row = &wvT[sc][0];
            float4 a0 = *(const float4*)(row + i0);
            float4 a1 = *(const float4*)(row + i0 + 4);
            float4 q0 = *(const float4*)(row + j0);
            float4 q1 = *(const float4*)(row + j0 + 4);
            float ar[8] = {ss * a0.x, ss * a0.y, ss * a0.z, ss * a0.w,
                           ss * a1.x, ss * a1.y, ss * a1.z, ss * a1.w};
            float br[8] = {q0.x, q0.y, q0.z, q0.w, q1.x, q1.y, q1.z, q1.w};
#pragma unroll
            for (int r = 0; r < 8; ++r)
#pragma unroll
                for (int c = 0; c < 8; ++c) acc[r][c] += ar[r] * br[c];
            if (tid < 128) vm += ss * wmT[sc][tid];
        }
    }
    __syncthreads();
    // phase 2a: delta, RHS init
    if (tid < 128) {
        float tm = 0.5f * (smg[b * 128 + tid] + vm);
        zd[tid] = lmg[l * 128 + tid] - tm;   // delta = label_mean - text_mean
        zv[tid] = vrow[tid];
    }
    // phase 2b: pack Sigma_t = I + 0.5*(sv sv^T + M) lower triangle
#pragma unroll
    for (int r = 0; r < 8; ++r) {
        int i = i0 + r;
#pragma unroll
        for (int c = 0; c < 8; ++c) {
            int j = j0 + c;
            if (j <= i)
                P[TRI(i, j)] = ((i == j) ? 1.f : 0.f) + 0.5f * (svr[i] * svr[j] + acc[r][c]);
        }
    }
    __syncthreads();
    // phase 2c: easy (Sherman-Morrison-side) terms
    float p_tr = 0.f, p_nv = 0.f, p_dd = 0.f, p_vd = 0.f, p_vsv = 0.f;
    if (tid < 128) {
        p_tr = P[TRI(tid, tid)];
        float vv = vrow[tid], de = zd[tid];
        p_nv = vv * vv; p_dd = de * de; p_vd = vv * de;
    }
    for (int e = tid; e < 8256; e += 256) {
        int i = (int)((sqrtf((float)(8 * e + 1)) - 1.f) * 0.5f);
        while (TRI(i + 1, 0) <= e) ++i;
        while (TRI(i, 0) > e) --i;
        int j = e - TRI(i, 0);
        float w = P[e] * vrow[i] * vrow[j];
        p_vsv += (i == j) ? w : 2.f * w;
    }
    float trP = bsum(p_tr, red);
    float nv = bsum(p_nv, red);
    float dds = bsum(p_dd, red);
    float vds = bsum(p_vd, red);
    float vsv = bsum(p_vsv, red);
    // phase 3: in-place Cholesky; column j of L becomes column j of L^{-1} after its pivot.
    // Simultaneous forward-substitution sweeps for zv (=v) and zd (=delta).
    for (int j = 0; j < 128; ++j) {
        __syncthreads();
        if (tid == 0) scal = 1.f / sqrtf(P[TRI(j, j)]);
        __syncthreads();
        float rd = scal;
        const int basej = TRI(j, 0);
        if (tid < 127) {
            if (tid < j) P[basej + tid] *= rd;              // scale row j of B-cols (fwd-sub scale)
            else P[TRI(tid + 1, j)] *= rd;                  // scale column j -> L[i][j]
        } else if (tid == 128) zv[j] *= rd;
        else if (tid == 129) zd[j] *= rd;
        __syncthreads();
        {
            int i = j + 1 + (tid >> 1);
            if (i < 128) {
                int basei = TRI(i, 0);
                float Lij = P[basei + j];
                float zvj = zv[j], zdj = zd[j];
                int m = tid & 1;
                int tm2 = m;                                 // TRI(m,0)
                for (; m <= i + 1; m += 2) {
                    if (m < j)        P[basei + m] -= Lij * P[basej + m];    // B-col sweep
                    else if (m == j)  zv[i] -= Lij * zvj;
                    else if (m <= i)  P[basei + m] -= Lij * P[tm2 + j];      // trailing Schur
                    else              zd[i] -= Lij * zdj;                    // m == i+1
                    tm2 += 2 * m + 3;
                }
            }
        }
        __syncthreads();
        if (tid < 127 && tid >= j) { int ii = tid + 1; P[TRI(ii, j)] = -P[TRI(ii, j)] * rd; }
        if (tid == 255) P[basej + j] = rd;
    }
    __syncthreads();
    // phase 4: reductions -> jsd
    float p_ti = 0.f, p_qv = 0.f, p_qd = 0.f;
    for (int e = tid; e < 8256; e += 256) { float x = P[e]; p_ti += x * x; }
    if (tid < 128) { float a = zv[tid]; p_qv = a * a; float d = zd[tid]; p_qd = d * d; }
    float trinv = bsum(p_ti, red);
    float qv = bsum(p_qv, red);
    float qd = bsum(p_qd, red);
    if (tid == 0) {
        float n = 1.f + nv;
        float A = trP - vsv / n;              // tr(Sq^{-1} Sp)
        float Bt = trinv + qv;                // tr(Sp^{-1} Sq)
        float mq = dds - vds * vds / n;       // delta^T Sq^{-1} delta
        outR[bid] = 0.25f * (A + Bt - 256.f + mq + qd);
    }
}

// ---------------------------------------------------------------- K5: broadcast outputs lm_b, lc_b
__global__ __launch_bounds__(256)
void k5_bcast(const float* __restrict__ lmg, const float* __restrict__ ldvg,
              float* __restrict__ out) {
    const int TOT = 16384 + 2097152;  // float4 counts: lm_b + lc_b
    float4* outLM = (float4*)(out + 512);
    float4* outLC = (float4*)(out + 512 + 65536);
    for (int idx = blockIdx.x * 256 + threadIdx.x; idx < TOT; idx += gridDim.x * 256) {
        if (idx < 16384) {
            int flat = idx * 4;
            int d0 = flat & 127;
            int l = (flat >> 7) & 63;
            outLM[idx] = *(const float4*)&lmg[l * 128 + d0];
        } else {
            int g = idx - 16384;
            int flat = g * 4;
            int j0v = flat & 127;
            int i = (flat >> 7) & 127;
            int l = (flat >> 14) & 63;
            float vi = ldvg[l * 128 + i];
            float4 vj = *(const float4*)&ldvg[l * 128 + j0v];
            float4 r;
            r.x = vi * vj.x + ((i == j0v + 0) ? 1.f : 0.f);
            r.y = vi * vj.y + ((i == j0v + 1) ? 1.f : 0.f);
            r.z = vi * vj.z + ((i == j0v + 2) ? 1.f : 0.f);
            r.w = vi * vj.w + ((i == j0v + 3) ? 1.f : 0.f);
            outLC[g] = r;
        }
    }
}

// ---------------------------------------------------------------- launch
extern "C" void kernel_launch(void* const* d_in, const int* in_sizes, int n_in,
                              void* d_out, int out_size, void* d_ws, size_t ws_size,
                              hipStream_t stream) {
    const float* wfm = (const float*)d_in[0];
    const float* wfd = (const float*)d_in[1];
    const float* sfm = (const float*)d_in[2];
    const float* sfd = (const float*)d_in[3];
    const float* W1 = (const float*)d_in[4];
    const float* B1 = (const float*)d_in[5];
    const float* W2 = (const float*)d_in[6];
    const float* B2 = (const float*)d_in[7];
    const float* W3 = (const float*)d_in[8];
    const float* B3 = (const float*)d_in[9];
    const float* W4 = (const float*)d_in[10];
    const float* B4 = (const float*)d_in[11];
    const float* lm = (const float*)d_in[12];
    const float* ldv = (const float*)d_in[13];
    float* out = (float*)d_out;
    float* ws = (float*)d_ws;

    float* wm = ws;                       // 262144
    float* wv = ws + 262144;              // 262144
    float* sm = ws + 524288;              // 1024
    float* sv = ws + 525312;              // 1024
    float4* rowsc = (float4*)(ws + 526336); // 2048 float4
    float4* labsc = (float4*)(ws + 534528); // 64 float4
    float* score = ws + 534784;           // 131072

    k5_bcast<<<2048, 256, 0, stream>>>(lm, ldv, out);
    k1_gemm<<<dim3(128, 2), 256, 0, stream>>>(wfm, wfd, W1, B1, W2, B2, wm, wv);
    k1b_sent<<<8, 128, 0, stream>>>(sfm, sfd, W3, B3, W4, B4, sm, sv);
    k2a_scal<<<528, 256, 0, stream>>>(wm, wv, lm, ldv, rowsc, labsc);
    k2b_score<<<512, 256, 0, stream>>>(wm, wv, lm, ldv, rowsc, labsc, score);
    k4_main<<<512, 256, 0, stream>>>(wm, wv, sm, sv, lm, ldv, score, out);
}

// Round 2
// 449.108 us; speedup vs baseline: 2.7959x; 2.7959x over previous
//
#include <hip/hip_runtime.h>
#include <hip/hip_bf16.h>

// B=8 S=256 H=768 D=128 L=64, all inputs f32.
// Outputs: relate_score (8*64) | lm_b (8*64*128) | lc_b (8*64*128*128), f32.

#define PITCH 132

// ---------------------------------------------------------------- K1: wm/wv GEMM
__global__ __launch_bounds__(256, 2)
void k1_gemm(const float* __restrict__ Am, const float* __restrict__ Av,
             const float* __restrict__ W1, const float* __restrict__ B1,
             const float* __restrict__ W2, const float* __restrict__ B2,
             float* __restrict__ wm, float* __restrict__ wv) {
    __shared__ float At[16][64];
    __shared__ __align__(16) float Wt[64][128];
    const int tid = threadIdx.x;
    const int sel = blockIdx.y;
    const float* A = sel ? Av : Am;
    const float* W = sel ? W2 : W1;
    const float* Bs = sel ? B2 : B1;
    float* D = sel ? wv : wm;
    const int R0 = blockIdx.x * 16;
    const int r = tid >> 4;
    const int j0 = (tid & 15) * 8;
    float acc[8] = {0.f,0.f,0.f,0.f,0.f,0.f,0.f,0.f};
    for (int k0 = 0; k0 < 768; k0 += 64) {
        __syncthreads();
#pragma unroll
        for (int it = 0; it < 4; ++it) {
            int f = tid + it * 256;
            int rr = f >> 6, cc = f & 63;
            At[rr][cc] = A[(size_t)(R0 + rr) * 768 + k0 + cc];
        }
#pragma unroll
        for (int it = 0; it < 8; ++it) {
            int f = tid + it * 256;
            int rr = f >> 5, c4 = (f & 31) * 4;
            *(float4*)&Wt[rr][c4] = *(const float4*)&W[(size_t)(k0 + rr) * 128 + c4];
        }
        __syncthreads();
#pragma unroll 8
        for (int kk = 0; kk < 64; ++kk) {
            float a = At[r][kk];
            float4 w0 = *(const float4*)&Wt[kk][j0];
            float4 w1 = *(const float4*)&Wt[kk][j0 + 4];
            acc[0] += a * w0.x; acc[1] += a * w0.y; acc[2] += a * w0.z; acc[3] += a * w0.w;
            acc[4] += a * w1.x; acc[5] += a * w1.y; acc[6] += a * w1.z; acc[7] += a * w1.w;
        }
    }
    size_t ob = (size_t)(R0 + r) * 128 + j0;
#pragma unroll
    for (int c = 0; c < 8; ++c) D[ob + c] = acc[c] + Bs[j0 + c];
}

// ---------------------------------------------------------------- K1b: sm/sv
__global__ __launch_bounds__(128)
void k1b_sent(const float* __restrict__ sfm, const float* __restrict__ sfd,
              const float* __restrict__ W3, const float* __restrict__ B3,
              const float* __restrict__ W4, const float* __restrict__ B4,
              float* __restrict__ sm, float* __restrict__ sv) {
    int b = blockIdx.x, d = threadIdx.x;
    const float* m = sfm + (size_t)b * 768;
    const float* v = sfd + (size_t)b * 768;
    float am = 0.f, av = 0.f;
    for (int h = 0; h < 768; ++h) {
        float fm = m[h], fv = v[h];
        am += fm * W3[(size_t)h * 128 + d];
        av += fv * W4[(size_t)h * 128 + d];
    }
    sm[b * 128 + d] = am + B3[d];
    sv[b * 128 + d] = av + B4[d];
}

// ---------------------------------------------------------------- K2a: per-row scalars
__global__ __launch_bounds__(256)
void k2a_scal(const float* __restrict__ wm, const float* __restrict__ wv,
              const float* __restrict__ lm, const float* __restrict__ ldv,
              float4* __restrict__ rowsc, float4* __restrict__ labsc) {
    int row = blockIdx.x * 4 + (threadIdx.x >> 6);
    int lane = threadIdx.x & 63;
    const float *pm, *pv;
    bool isLab;
    int l = 0;
    if (row < 2048) {
        pm = wm + (size_t)row * 128; pv = wv + (size_t)row * 128; isLab = false;
    } else if (row < 2112) {
        l = row - 2048;
        pm = lm + (size_t)l * 128; pv = ldv + (size_t)l * 128; isLab = true;
    } else return;
    float m0 = pm[lane], m1 = pm[lane + 64];
    float v0 = pv[lane], v1 = pv[lane + 64];
    float s_m = m0 * m0 + m1 * m1;
    float s_v = v0 * v0 + v1 * v1;
    float s_mv = m0 * v0 + m1 * v1;
#pragma unroll
    for (int o = 32; o; o >>= 1) {
        s_m += __shfl_xor(s_m, o);
        s_v += __shfl_xor(s_v, o);
        s_mv += __shfl_xor(s_mv, o);
    }
    if (lane == 0) {
        float4 r = make_float4(1.f + s_v, s_m, s_mv, 0.f);
        if (isLab) labsc[l] = r; else rowsc[row] = r;
    }
}

// ---------------------------------------------------------------- K2b: logits + softmax -> score
__global__ __launch_bounds__(256, 2)
void k2b_score(const float* __restrict__ wm, const float* __restrict__ wv,
               const float* __restrict__ lm, const float* __restrict__ ldv,
               const float4* __restrict__ rowsc, const float4* __restrict__ labsc,
               float* __restrict__ score) {
    __shared__ float mu[128], vp[128];
    __shared__ float wmT[256][17], wvT[256][17];
    __shared__ float red[4];
    const int tid = threadIdx.x;
    const int b = blockIdx.x >> 6, l = blockIdx.x & 63;
    if (tid < 128) {
        mu[tid] = lm[l * 128 + tid];
        vp[tid] = ldv[l * 128 + tid];
    }
    float dot = 0.f, md = 0.f, pvv = 0.f, vq = 0.f;
    const float* wmr = wm + (size_t)(b * 256 + tid) * 128;
    const float* wvr = wv + (size_t)(b * 256 + tid) * 128;
    for (int d0 = 0; d0 < 128; d0 += 16) {
        __syncthreads();
#pragma unroll
        for (int q = 0; q < 4; ++q) {
            float4 xm = *(const float4*)&wmr[d0 + q * 4];
            float4 xv = *(const float4*)&wvr[d0 + q * 4];
            wmT[tid][q * 4 + 0] = xm.x; wmT[tid][q * 4 + 1] = xm.y;
            wmT[tid][q * 4 + 2] = xm.z; wmT[tid][q * 4 + 3] = xm.w;
            wvT[tid][q * 4 + 0] = xv.x; wvT[tid][q * 4 + 1] = xv.y;
            wvT[tid][q * 4 + 2] = xv.z; wvT[tid][q * 4 + 3] = xv.w;
        }
        __syncthreads();
#pragma unroll
        for (int dd = 0; dd < 16; ++dd) {
            float am = mu[d0 + dd], av = vp[d0 + dd];
            float xm = wmT[tid][dd], xv = wvT[tid][dd];
            md += am * xm; dot += av * xv; pvv += am * xv; vq += av * xm;
        }
    }
    float4 rs = rowsc[b * 256 + tid];
    float4 ls = labsc[l];
    float nq = rs.x, mmq = rs.y, vmq = rs.z;
    float np = ls.x, mmp = ls.y, vmp = ls.z;
    float d2 = mmq - 2.f * md + mmp;
    float vqd = vmq - pvv, vpd = vq - vmp;
    float inq = 1.f / nq, inp = 1.f / np;
    float maha_q = d2 - vqd * vqd * inq;
    float maha_p = d2 - vpd * vpd * inp;
    float logit = 0.25f * ((np - 1.f) + (nq - 1.f)
                           - (nq - 1.f + dot * dot) * inq
                           - (np - 1.f + dot * dot) * inp
                           + maha_q + maha_p);
    float mx = logit;
#pragma unroll
    for (int o = 32; o; o >>= 1) mx = fmaxf(mx, __shfl_xor(mx, o));
    if ((tid & 63) == 0) red[tid >> 6] = mx;
    __syncthreads();
    mx = fmaxf(fmaxf(red[0], red[1]), fmaxf(red[2], red[3]));
    float e = expf(logit - mx);
    float s = e;
#pragma unroll
    for (int o = 32; o; o >>= 1) s += __shfl_xor(s, o);
    __syncthreads();
    if ((tid & 63) == 0) red[tid >> 6] = s;
    __syncthreads();
    float tot = red[0] + red[1] + red[2] + red[3];
    score[(size_t)blockIdx.x * 256 + tid] = e / tot;
}

// ---------------------------------------------------------------- block reduce helper
__device__ __forceinline__ float bsum(float v, float* red) {
#pragma unroll
    for (int o = 32; o; o >>= 1) v += __shfl_xor(v, o);
    __syncthreads();
    if ((threadIdx.x & 63) == 0) red[threadIdx.x >> 6] = v;
    __syncthreads();
    return red[0] + red[1] + red[2] + red[3];
}

// ---------------------------------------------------------------- K4: Sigma build + parallel LDL^T + in-place L^{-1} rows
// grid 512 = (b,l), block 256. Dynamic LDS: full 128x132 square + small buffers.
// Lower triangle: Schur workspace / LDL^T columns. Strict upper: U[m][i] partials
// for X = L^{-1}: U[m][i] = sum_k L[i][k] X[k][m]; X row j = -U[.][j] finalized at pivot j
// and consumed immediately (never stored). tr(Sigma^{-1}) = sum_j invd_j * ||X_j||^2.
__global__ __launch_bounds__(256, 2)
void k4_main(const float* __restrict__ wm, const float* __restrict__ wv,
             const float* __restrict__ smg, const float* __restrict__ svg,
             const float* __restrict__ lmg, const float* __restrict__ ldvg,
             const float* __restrict__ score, float* __restrict__ outR) {
    extern __shared__ float smem[];
    float* Amat = smem;                        // 128*132
    float* scoreL = Amat + 128 * PITCH;        // 256
    float* svr    = scoreL + 256;              // 128
    float* vrow   = svr + 128;                 // 128
    float* zv     = vrow + 128;                // 128
    float* zd     = zv + 128;                  // 128
    float* wbuf   = zd + 128;                  // 128 (scaled column L[i][j])
    float* xrow   = wbuf + 128;                // 128 (current X row)
    float* dinv   = xrow + 128;                // 128
    float* red    = dinv + 128;                // 4
    // phase-1 staging aliases Amat (first 16KB):
    float* wvT = Amat;                         // [16][128]
    float* wmT = Amat + 16 * 128;              // [16][128]

    const int tid = threadIdx.x;
    const int bid = blockIdx.x;
    const int b = bid >> 6, l = bid & 63;
    const float* wvb = wv + (size_t)b * 256 * 128;
    const float* wmb = wm + (size_t)b * 256 * 128;
    scoreL[tid] = score[(size_t)bid * 256 + tid];
    if (tid < 128) {
        svr[tid] = svg[b * 128 + tid];
        vrow[tid] = ldvg[l * 128 + tid];
    }
    const int tx = tid & 15, ty = tid >> 4;
    const int i0 = ty * 8, j0 = tx * 8;
    float acc[8][8];
#pragma unroll
    for (int r = 0; r < 8; ++r)
#pragma unroll
        for (int c = 0; c < 8; ++c) acc[r][c] = 0.f;
    float vm = 0.f;
    // ---- phase 1: M = Wv^T diag(score) Wv + v_mean
    for (int s0 = 0; s0 < 256; s0 += 16) {
        __syncthreads();
#pragma unroll
        for (int it = 0; it < 2; ++it) {
            int f = tid + it * 256;
            int rr = f >> 5, c4 = (f & 31) * 4;
            *(float4*)&wvT[rr * 128 + c4] = *(const float4*)&wvb[(size_t)(s0 + rr) * 128 + c4];
            *(float4*)&wmT[rr * 128 + c4] = *(const float4*)&wmb[(size_t)(s0 + rr) * 128 + c4];
        }
        __syncthreads();
#pragma unroll 2
        for (int sc = 0; sc < 16; ++sc) {
            float ss = scoreL[s0 + sc];
            const float* row = &wvT[sc * 128];
            float4 a0 = *(const float4*)(row + i0);
            float4 a1 = *(const float4*)(row + i0 + 4);
            float4 q0 = *(const float4*)(row + j0);
            float4 q1 = *(const float4*)(row + j0 + 4);
            float ar[8] = {ss * a0.x, ss * a0.y, ss * a0.z, ss * a0.w,
                           ss * a1.x, ss * a1.y, ss * a1.z, ss * a1.w};
            float br[8] = {q0.x, q0.y, q0.z, q0.w, q1.x, q1.y, q1.z, q1.w};
#pragma unroll
            for (int r = 0; r < 8; ++r)
#pragma unroll
                for (int c = 0; c < 8; ++c) acc[r][c] += ar[r] * br[c];
            if (tid < 128) vm += ss * wmT[sc * 128 + tid];
        }
    }
    __syncthreads();   // staging dead; Amat reusable
    // ---- phase 2a: delta & RHS
    if (tid < 128) {
        float tm = 0.5f * (smg[b * 128 + tid] + vm);
        zd[tid] = lmg[l * 128 + tid] - tm;
        zv[tid] = vrow[tid];
    }
    // ---- phase 2b: write full square: lower = Sigma_t, strict upper = 0
#pragma unroll
    for (int r = 0; r < 8; ++r) {
        int i = i0 + r;
        float vals[8];
#pragma unroll
        for (int c = 0; c < 8; ++c) {
            int j = j0 + c;
            float sig = ((i == j) ? 1.f : 0.f) + 0.5f * (svr[i] * svr[j] + acc[r][c]);
            vals[c] = (j <= i) ? sig : 0.f;
        }
        *(float4*)&Amat[i * PITCH + j0]     = make_float4(vals[0], vals[1], vals[2], vals[3]);
        *(float4*)&Amat[i * PITCH + j0 + 4] = make_float4(vals[4], vals[5], vals[6], vals[7]);
    }
    __syncthreads();
    // ---- phase 2c: closed-form (label-side) terms.  vsv = v^T Sigma v = 2*s1 - s2
    float p_tr = 0.f, p_nv = 0.f, p_dd = 0.f, p_vd = 0.f, p_s1 = 0.f, p_s2 = 0.f;
    if (tid < 128) {
        p_tr = Amat[tid * PITCH + tid];
        float vv = vrow[tid], de = zd[tid];
        p_nv = vv * vv; p_dd = de * de; p_vd = vv * de;
        p_s2 = p_tr * vv * vv;
    }
    {
        int i = tid >> 1, c0 = (tid & 1) * 64;
        float vi = vrow[i], s = 0.f;
        for (int c = c0; c < c0 + 64; c += 4) {
            float4 a = *(const float4*)&Amat[i * PITCH + c];
            s += a.x * vrow[c] + a.y * vrow[c + 1] + a.z * vrow[c + 2] + a.w * vrow[c + 3];
        }
        p_s1 = vi * s;
    }
    float trP = bsum(p_tr, red);
    float nv  = bsum(p_nv, red);
    float dds = bsum(p_dd, red);
    float vds = bsum(p_vd, red);
    float s1  = bsum(p_s1, red);
    float s2  = bsum(p_s2, red);
    float vsv = 2.f * s1 - s2;
    // ---- phase 3: pivot loop (2 barriers/pivot, all 256 threads active in B)
    float accTr = 0.f;
    for (int j = 0; j < 128; ++j) {
        __syncthreads();                           // phase A: prior updates complete
        float d = Amat[j * PITCH + j];
        float invd = 1.f / d;
        if (tid < 128) {
            float cv = Amat[tid * PITCH + j];      // column j (upper: U, lower: raw c)
            if (tid < j) {
                float x = -cv;                     // X[j][tid] final
                xrow[tid] = x;
                accTr += invd * x * x;
            } else if (tid == j) {
                xrow[j] = 1.f;                     // X[j][j]
                accTr += invd;
                dinv[j] = invd;
            } else {
                wbuf[tid] = cv * invd;             // L[tid][j]
            }
        }
        __syncthreads();                           // phase B
        float zvj = zv[j], zdj = zd[j];
        int v = tid & 127, h = tid >> 7;
        if (v > j) {                               // Schur row i = v : k in [j+1, i]
            int i = v;
            float c = Amat[i * PITCH + j];
            if (h == 0) {
                float w = wbuf[i];
                zv[i] -= w * zvj;
                zd[i] -= w * zdj;
            }
            int lo = j + 1, hi = i;
            int mid = (lo + hi + 1) >> 1;
            int k = h ? mid : lo;
            int k1 = h ? hi : mid - 1;
            float* Ai = &Amat[i * PITCH];
            for (; k <= k1 && (k & 3); ++k) Ai[k] -= c * wbuf[k];
            for (; k + 3 <= k1; k += 4) {
                float4 a = *(float4*)&Ai[k];
                float4 w = *(const float4*)&wbuf[k];
                a.x -= c * w.x; a.y -= c * w.y; a.z -= c * w.z; a.w -= c * w.w;
                *(float4*)&Ai[k] = a;
            }
            for (; k <= k1; ++k) Ai[k] -= c * wbuf[k];
        } else {                                   // U row m = v <= j : i in [j+1, 127]
            int m = v;
            float xm = xrow[m];
            int lo = j + 1, hi = 127;
            int mid = (lo + hi + 1) >> 1;
            int k = h ? mid : lo;
            int k1 = h ? hi : mid - 1;
            float* Am = &Amat[m * PITCH];
            for (; k <= k1 && (k & 3); ++k) Am[k] += wbuf[k] * xm;
            for (; k + 3 <= k1; k += 4) {
                float4 a = *(float4*)&Am[k];
                float4 w = *(const float4*)&wbuf[k];
                a.x += xm * w.x; a.y += xm * w.y; a.z += xm * w.z; a.w += xm * w.w;
                *(float4*)&Am[k] = a;
            }
            for (; k <= k1; ++k) Am[k] += wbuf[k] * xm;
        }
    }
    __syncthreads();
    // ---- phase 4: final reductions
    float p_ti = accTr, p_qv = 0.f, p_qd = 0.f;
    if (tid < 128) {
        float iv = dinv[tid];
        float a = zv[tid];  p_qv = iv * a * a;
        float dd2 = zd[tid]; p_qd = iv * dd2 * dd2;
    }
    float trinv = bsum(p_ti, red);
    float qv = bsum(p_qv, red);
    float qd = bsum(p_qd, red);
    if (tid == 0) {
        float n = 1.f + nv;
        float Aterm = trP - vsv / n;          // tr(Sq^{-1} Sp)
        float Bt = trinv + qv;                // tr(Sp^{-1} Sq)
        float mq = dds - vds * vds / n;       // delta^T Sq^{-1} delta
        outR[bid] = 0.25f * (Aterm + Bt - 256.f + mq + qd);
    }
}

// ---------------------------------------------------------------- K5: broadcast outputs lm_b, lc_b
__global__ __launch_bounds__(256)
void k5_bcast(const float* __restrict__ lmg, const float* __restrict__ ldvg,
              float* __restrict__ out) {
    const int TOT = 16384 + 2097152;
    float4* outLM = (float4*)(out + 512);
    float4* outLC = (float4*)(out + 512 + 65536);
    for (int idx = blockIdx.x * 256 + threadIdx.x; idx < TOT; idx += gridDim.x * 256) {
        if (idx < 16384) {
            int flat = idx * 4;
            int d0 = flat & 127;
            int l = (flat >> 7) & 63;
            outLM[idx] = *(const float4*)&lmg[l * 128 + d0];
        } else {
            int g = idx - 16384;
            int flat = g * 4;
            int j0v = flat & 127;
            int i = (flat >> 7) & 127;
            int l = (flat >> 14) & 63;
            float vi = ldvg[l * 128 + i];
            float4 vj = *(const float4*)&ldvg[l * 128 + j0v];
            float4 r;
            r.x = vi * vj.x + ((i == j0v + 0) ? 1.f : 0.f);
            r.y = vi * vj.y + ((i == j0v + 1) ? 1.f : 0.f);
            r.z = vi * vj.z + ((i == j0v + 2) ? 1.f : 0.f);
            r.w = vi * vj.w + ((i == j0v + 3) ? 1.f : 0.f);
            outLC[g] = r;
        }
    }
}

// ---------------------------------------------------------------- launch
extern "C" void kernel_launch(void* const* d_in, const int* in_sizes, int n_in,
                              void* d_out, int out_size, void* d_ws, size_t ws_size,
                              hipStream_t stream) {
    const float* wfm = (const float*)d_in[0];
    const float* wfd = (const float*)d_in[1];
    const float* sfm = (const float*)d_in[2];
    const float* sfd = (const float*)d_in[3];
    const float* W1 = (const float*)d_in[4];
    const float* B1 = (const float*)d_in[5];
    const float* W2 = (const float*)d_in[6];
    const float* B2 = (const float*)d_in[7];
    const float* W3 = (const float*)d_in[8];
    const float* B3 = (const float*)d_in[9];
    const float* W4 = (const float*)d_in[10];
    const float* B4 = (const float*)d_in[11];
    const float* lm = (const float*)d_in[12];
    const float* ldv = (const float*)d_in[13];
    float* out = (float*)d_out;
    float* ws = (float*)d_ws;

    float* wm = ws;                         // 262144
    float* wv = ws + 262144;                // 262144
    float* sm = ws + 524288;                // 1024
    float* sv = ws + 525312;                // 1024
    float4* rowsc = (float4*)(ws + 526336); // 2048 float4
    float4* labsc = (float4*)(ws + 534528); // 64 float4
    float* score = ws + 534784;             // 131072

    constexpr int SH_FLOATS = 128 * PITCH + 256 + 128 * 7 + 4;
    constexpr size_t SH_BYTES = SH_FLOATS * sizeof(float);   // 72208 B -> 2 blocks/CU
    (void)hipFuncSetAttribute((const void*)k4_main,
                              hipFuncAttributeMaxDynamicSharedMemorySize,
                              (int)SH_BYTES);

    k5_bcast<<<2048, 256, 0, stream>>>(lm, ldv, out);
    k1_gemm<<<dim3(128, 2), 256, 0, stream>>>(wfm, wfd, W1, B1, W2, B2, wm, wv);
    k1b_sent<<<8, 128, 0, stream>>>(sfm, sfd, W3, B3, W4, B4, sm, sv);
    k2a_scal<<<528, 256, 0, stream>>>(wm, wv, lm, ldv, rowsc, labsc);
    k2b_score<<<512, 256, 0, stream>>>(wm, wv, lm, ldv, rowsc, labsc, score);
    k4_main<<<512, 256, SH_BYTES, stream>>>(wm, wv, sm, sv, lm, ldv, score, out);
}

// Round 3
// 305.587 us; speedup vs baseline: 4.1090x; 1.4697x over previous
//
#include <hip/hip_runtime.h>
#include <hip/hip_bf16.h>

// B=8 S=256 H=768 D=128 L=64, all inputs f32.
// Outputs: relate_score (8*64) | lm_b (8*64*128) | lc_b (8*64*128*128), f32.

#define PITCH 132

// ---------------------------------------------------------------- K1: wm/wv GEMM
__global__ __launch_bounds__(256, 2)
void k1_gemm(const float* __restrict__ Am, const float* __restrict__ Av,
             const float* __restrict__ W1, const float* __restrict__ B1,
             const float* __restrict__ W2, const float* __restrict__ B2,
             float* __restrict__ wm, float* __restrict__ wv) {
    __shared__ float At[16][64];
    __shared__ __align__(16) float Wt[64][128];
    const int tid = threadIdx.x;
    const int sel = blockIdx.y;
    const float* A = sel ? Av : Am;
    const float* W = sel ? W2 : W1;
    const float* Bs = sel ? B2 : B1;
    float* D = sel ? wv : wm;
    const int R0 = blockIdx.x * 16;
    const int r = tid >> 4;
    const int j0 = (tid & 15) * 8;
    float acc[8] = {0.f,0.f,0.f,0.f,0.f,0.f,0.f,0.f};
    for (int k0 = 0; k0 < 768; k0 += 64) {
        __syncthreads();
#pragma unroll
        for (int it = 0; it < 4; ++it) {
            int f = tid + it * 256;
            int rr = f >> 6, cc = f & 63;
            At[rr][cc] = A[(size_t)(R0 + rr) * 768 + k0 + cc];
        }
#pragma unroll
        for (int it = 0; it < 8; ++it) {
            int f = tid + it * 256;
            int rr = f >> 5, c4 = (f & 31) * 4;
            *(float4*)&Wt[rr][c4] = *(const float4*)&W[(size_t)(k0 + rr) * 128 + c4];
        }
        __syncthreads();
#pragma unroll 8
        for (int kk = 0; kk < 64; ++kk) {
            float a = At[r][kk];
            float4 w0 = *(const float4*)&Wt[kk][j0];
            float4 w1 = *(const float4*)&Wt[kk][j0 + 4];
            acc[0] += a * w0.x; acc[1] += a * w0.y; acc[2] += a * w0.z; acc[3] += a * w0.w;
            acc[4] += a * w1.x; acc[5] += a * w1.y; acc[6] += a * w1.z; acc[7] += a * w1.w;
        }
    }
    size_t ob = (size_t)(R0 + r) * 128 + j0;
#pragma unroll
    for (int c = 0; c < 8; ++c) D[ob + c] = acc[c] + Bs[j0 + c];
}

// ---------------------------------------------------------------- K1b: sm/sv
__global__ __launch_bounds__(128)
void k1b_sent(const float* __restrict__ sfm, const float* __restrict__ sfd,
              const float* __restrict__ W3, const float* __restrict__ B3,
              const float* __restrict__ W4, const float* __restrict__ B4,
              float* __restrict__ sm, float* __restrict__ sv) {
    int b = blockIdx.x, d = threadIdx.x;
    const float* m = sfm + (size_t)b * 768;
    const float* v = sfd + (size_t)b * 768;
    float am = 0.f, av = 0.f;
    for (int h = 0; h < 768; ++h) {
        float fm = m[h], fv = v[h];
        am += fm * W3[(size_t)h * 128 + d];
        av += fv * W4[(size_t)h * 128 + d];
    }
    sm[b * 128 + d] = am + B3[d];
    sv[b * 128 + d] = av + B4[d];
}

// ---------------------------------------------------------------- K2a: per-row scalars
__global__ __launch_bounds__(256)
void k2a_scal(const float* __restrict__ wm, const float* __restrict__ wv,
              const float* __restrict__ lm, const float* __restrict__ ldv,
              float4* __restrict__ rowsc, float4* __restrict__ labsc) {
    int row = blockIdx.x * 4 + (threadIdx.x >> 6);
    int lane = threadIdx.x & 63;
    const float *pm, *pv;
    bool isLab;
    int l = 0;
    if (row < 2048) {
        pm = wm + (size_t)row * 128; pv = wv + (size_t)row * 128; isLab = false;
    } else if (row < 2112) {
        l = row - 2048;
        pm = lm + (size_t)l * 128; pv = ldv + (size_t)l * 128; isLab = true;
    } else return;
    float m0 = pm[lane], m1 = pm[lane + 64];
    float v0 = pv[lane], v1 = pv[lane + 64];
    float s_m = m0 * m0 + m1 * m1;
    float s_v = v0 * v0 + v1 * v1;
    float s_mv = m0 * v0 + m1 * v1;
#pragma unroll
    for (int o = 32; o; o >>= 1) {
        s_m += __shfl_xor(s_m, o);
        s_v += __shfl_xor(s_v, o);
        s_mv += __shfl_xor(s_mv, o);
    }
    if (lane == 0) {
        float4 r = make_float4(1.f + s_v, s_m, s_mv, 0.f);
        if (isLab) labsc[l] = r; else rowsc[row] = r;
    }
}

// ---------------------------------------------------------------- K2b: logits + softmax -> score
__global__ __launch_bounds__(256, 2)
void k2b_score(const float* __restrict__ wm, const float* __restrict__ wv,
               const float* __restrict__ lm, const float* __restrict__ ldv,
               const float4* __restrict__ rowsc, const float4* __restrict__ labsc,
               float* __restrict__ score) {
    __shared__ float mu[128], vp[128];
    __shared__ float wmT[256][17], wvT[256][17];
    __shared__ float red[4];
    const int tid = threadIdx.x;
    const int b = blockIdx.x >> 6, l = blockIdx.x & 63;
    if (tid < 128) {
        mu[tid] = lm[l * 128 + tid];
        vp[tid] = ldv[l * 128 + tid];
    }
    float dot = 0.f, md = 0.f, pvv = 0.f, vq = 0.f;
    const float* wmr = wm + (size_t)(b * 256 + tid) * 128;
    const float* wvr = wv + (size_t)(b * 256 + tid) * 128;
    for (int d0 = 0; d0 < 128; d0 += 16) {
        __syncthreads();
#pragma unroll
        for (int q = 0; q < 4; ++q) {
            float4 xm = *(const float4*)&wmr[d0 + q * 4];
            float4 xv = *(const float4*)&wvr[d0 + q * 4];
            wmT[tid][q * 4 + 0] = xm.x; wmT[tid][q * 4 + 1] = xm.y;
            wmT[tid][q * 4 + 2] = xm.z; wmT[tid][q * 4 + 3] = xm.w;
            wvT[tid][q * 4 + 0] = xv.x; wvT[tid][q * 4 + 1] = xv.y;
            wvT[tid][q * 4 + 2] = xv.z; wvT[tid][q * 4 + 3] = xv.w;
        }
        __syncthreads();
#pragma unroll
        for (int dd = 0; dd < 16; ++dd) {
            float am = mu[d0 + dd], av = vp[d0 + dd];
            float xm = wmT[tid][dd], xv = wvT[tid][dd];
            md += am * xm; dot += av * xv; pvv += am * xv; vq += av * xm;
        }
    }
    float4 rs = rowsc[b * 256 + tid];
    float4 ls = labsc[l];
    float nq = rs.x, mmq = rs.y, vmq = rs.z;
    float np = ls.x, mmp = ls.y, vmp = ls.z;
    float d2 = mmq - 2.f * md + mmp;
    float vqd = vmq - pvv, vpd = vq - vmp;
    float inq = 1.f / nq, inp = 1.f / np;
    float maha_q = d2 - vqd * vqd * inq;
    float maha_p = d2 - vpd * vpd * inp;
    float logit = 0.25f * ((np - 1.f) + (nq - 1.f)
                           - (nq - 1.f + dot * dot) * inq
                           - (np - 1.f + dot * dot) * inp
                           + maha_q + maha_p);
    float mx = logit;
#pragma unroll
    for (int o = 32; o; o >>= 1) mx = fmaxf(mx, __shfl_xor(mx, o));
    if ((tid & 63) == 0) red[tid >> 6] = mx;
    __syncthreads();
    mx = fmaxf(fmaxf(red[0], red[1]), fmaxf(red[2], red[3]));
    float e = expf(logit - mx);
    float s = e;
#pragma unroll
    for (int o = 32; o; o >>= 1) s += __shfl_xor(s, o);
    __syncthreads();
    if ((tid & 63) == 0) red[tid >> 6] = s;
    __syncthreads();
    float tot = red[0] + red[1] + red[2] + red[3];
    score[(size_t)blockIdx.x * 256 + tid] = e / tot;
}

// ---------------------------------------------------------------- block reduce helper
__device__ __forceinline__ float bsum(float v, float* red) {
#pragma unroll
    for (int o = 32; o; o >>= 1) v += __shfl_xor(v, o);
    __syncthreads();
    if ((threadIdx.x & 63) == 0) red[threadIdx.x >> 6] = v;
    __syncthreads();
    float t = red[0] + red[1] + red[2] + red[3];
    __syncthreads();
    return t;
}

// ---------------------------------------------------------------- K4: Sigma build + blocked Cholesky + blocked triangular inverse
// grid 512 = (b,l), block 256. Dynamic LDS:
//   Amat[128][132]: full symmetric Sigma -> (lower) L panels, (diag blocks) T=Lpp^-1 transposed,
//                   (upper) X^T where X = L^-1 block-lower: Amat[16J+b][16k+c] = X[k,J][c,b].
//   Wb[16][132]: transposed current panel (L^T rows) for the rank-16 Schur GEMM;
//                aliases scoreL/svr (phase 1-2) and Sbuf (sweeps).
__global__ __launch_bounds__(256, 2)
void k4_main(const float* __restrict__ wm, const float* __restrict__ wv,
             const float* __restrict__ smg, const float* __restrict__ svg,
             const float* __restrict__ lmg, const float* __restrict__ ldvg,
             const float* __restrict__ score, float* __restrict__ outR) {
    extern __shared__ float smem[];
    float* Amat   = smem;                 // 16896
    float* Wb     = smem + 16896;         // 2112
    float* scoreL = Wb;                   // 256   (phase 1 only)
    float* svr    = Wb + 256;             // 128   (phase 2 only)
    float* Sbuf   = Wb;                   // up to 1792 (sweeps only)
    float* vrow   = smem + 19008;         // 128
    float* zv     = smem + 19136;         // 128
    float* zd     = smem + 19264;         // 128
    float* red    = smem + 19392;         // 4
    // phase-1 staging aliases Amat (first 16KB)
    float* wvT = Amat;                    // [16][128]
    float* wmT = Amat + 2048;             // [16][128]

    const int tid = threadIdx.x;
    const int bid = blockIdx.x;
    const int b = bid >> 6, l = bid & 63;
    const float* wvb = wv + (size_t)b * 256 * 128;
    const float* wmb = wm + (size_t)b * 256 * 128;
    scoreL[tid] = score[(size_t)bid * 256 + tid];
    if (tid < 128) {
        svr[tid] = svg[b * 128 + tid];
        vrow[tid] = ldvg[l * 128 + tid];
    }
    const int tx = tid & 15, ty = tid >> 4;
    const int i0 = ty * 8, j0 = tx * 8;
    float acc[8][8];
#pragma unroll
    for (int r = 0; r < 8; ++r)
#pragma unroll
        for (int c = 0; c < 8; ++c) acc[r][c] = 0.f;
    float vm = 0.f;
    // ---- phase 1: M = Wv^T diag(score) Wv + v_mean
    for (int s0 = 0; s0 < 256; s0 += 16) {
        __syncthreads();
#pragma unroll
        for (int it = 0; it < 2; ++it) {
            int f = tid + it * 256;
            int rr = f >> 5, c4 = (f & 31) * 4;
            *(float4*)&wvT[rr * 128 + c4] = *(const float4*)&wvb[(size_t)(s0 + rr) * 128 + c4];
            *(float4*)&wmT[rr * 128 + c4] = *(const float4*)&wmb[(size_t)(s0 + rr) * 128 + c4];
        }
        __syncthreads();
#pragma unroll 2
        for (int sc = 0; sc < 16; ++sc) {
            float ss = scoreL[s0 + sc];
            const float* row = &wvT[sc * 128];
            float4 a0 = *(const float4*)(row + i0);
            float4 a1 = *(const float4*)(row + i0 + 4);
            float4 q0 = *(const float4*)(row + j0);
            float4 q1 = *(const float4*)(row + j0 + 4);
            float ar[8] = {ss * a0.x, ss * a0.y, ss * a0.z, ss * a0.w,
                           ss * a1.x, ss * a1.y, ss * a1.z, ss * a1.w};
            float br[8] = {q0.x, q0.y, q0.z, q0.w, q1.x, q1.y, q1.z, q1.w};
#pragma unroll
            for (int r = 0; r < 8; ++r)
#pragma unroll
                for (int c = 0; c < 8; ++c) acc[r][c] += ar[r] * br[c];
            if (tid < 128) vm += ss * wmT[sc * 128 + tid];
        }
    }
    __syncthreads();   // staging dead; Amat reusable
    // ---- phase 2a: delta & RHS
    if (tid < 128) {
        float tm = 0.5f * (smg[b * 128 + tid] + vm);
        zd[tid] = lmg[l * 128 + tid] - tm;
        zv[tid] = vrow[tid];
    }
    // ---- phase 2b: write FULL symmetric square Sigma_t = I + 0.5*(sv sv^T + M)
#pragma unroll
    for (int r = 0; r < 8; ++r) {
        int i = i0 + r;
        float vals[8];
#pragma unroll
        for (int c = 0; c < 8; ++c) {
            int j = j0 + c;
            vals[c] = ((i == j) ? 1.f : 0.f) + 0.5f * (svr[i] * svr[j] + acc[r][c]);
        }
        *(float4*)&Amat[i * PITCH + j0]     = make_float4(vals[0], vals[1], vals[2], vals[3]);
        *(float4*)&Amat[i * PITCH + j0 + 4] = make_float4(vals[4], vals[5], vals[6], vals[7]);
    }
    __syncthreads();
    // ---- phase 2c: label-side closed-form terms (Sherman-Morrison side)
    float p_tr = 0.f, p_nv = 0.f, p_dd = 0.f, p_vd = 0.f, p_s1 = 0.f;
    if (tid < 128) {
        p_tr = Amat[tid * PITCH + tid];
        float vv = vrow[tid], de = zd[tid];
        p_nv = vv * vv; p_dd = de * de; p_vd = vv * de;
    }
    {
        int i = tid >> 1, h = tid & 1;
        const float* Ar = &Amat[i * PITCH + h * 64];
        const float* vr = &vrow[h * 64];
        float s = 0.f;
        for (int k2 = 0; k2 < 64; k2 += 4) {
            float4 a = *(const float4*)&Ar[k2];
            s += a.x * vr[k2] + a.y * vr[k2 + 1] + a.z * vr[k2 + 2] + a.w * vr[k2 + 3];
        }
        p_s1 = vrow[i] * s;
    }
    float trP = bsum(p_tr, red);
    float nv  = bsum(p_nv, red);
    float dds = bsum(p_dd, red);
    float vds = bsum(p_vd, red);
    float vsv = bsum(p_s1, red);   // v^T Sigma v (full-row dot)
    // ---- phase 3: blocked Cholesky, panel width 16
    for (int p = 0; p < 8; ++p) {
        const int base = 16 * p;
        __syncthreads();
        if (tid < 64) {
            // F1 (wave 0): in-register chol of diag block; lane c holds column c
            const int c = tid;
            float cv[16];
#pragma unroll
            for (int r = 0; r < 16; ++r) cv[r] = Amat[(base + r) * PITCH + base + c];
#pragma unroll
            for (int t = 0; t < 16; ++t) {
                float lt[16];
#pragma unroll
                for (int r = 0; r < 16; ++r) lt[r] = __shfl(cv[r], t);
                float invs = 1.f / sqrtf(lt[t]);
                if (c == t) {
#pragma unroll
                    for (int r = 0; r < 16; ++r) cv[r] = (r >= t) ? lt[r] * invs : 0.f;
                } else if (c > t && c < 16) {
                    float lc = lt[c] * invs;
#pragma unroll
                    for (int r = 0; r < 16; ++r)
                        if (r > t) cv[r] -= (lt[r] * invs) * lc;
                }
            }
            // T = Lpp^{-1}: lane c solves L x = e_c (x = column c of T)
            float x[16], acb[16];
#pragma unroll
            for (int r = 0; r < 16; ++r) acb[r] = 0.f;
#pragma unroll
            for (int r = 0; r < 16; ++r) {
                float Lrr = __shfl(cv[r], r);
                float xr = (((c == r) ? 1.f : 0.f) - acb[r]) / Lrr;
                x[r] = xr;
#pragma unroll
                for (int q = r + 1; q < 16; ++q) acb[q] += __shfl(cv[q], r) * xr;
            }
            if (c < 16) {
#pragma unroll
                for (int r = 0; r < 16; ++r)
                    Amat[(base + c) * PITCH + base + r] = x[r];   // T^T into diag block
            }
            // z' = T * z_panel (lanes 0..15: zv, 16..31: zd); in-wave lockstep: reads before writes
            if (c < 32) {
                int t2 = c & 15;
                float* zp = (c < 16) ? zv : zd;
                float a0 = 0.f;
#pragma unroll
                for (int a = 0; a < 16; ++a)
                    a0 += Amat[(base + a) * PITCH + base + t2] * zp[base + a];
                zp[base + t2] = a0;
            }
        }
        __syncthreads();
        const int R = 112 - base;     // trailing rows
        // panel solve: L[i,panel] = A[i,panel] * T^T; also write transposed copy W
        if (R > 0 && tid < R) {
            int i = base + 16 + tid;
            const float* Ar = &Amat[i * PITCH + base];
            float4 q0 = *(const float4*)&Ar[0];
            float4 q1 = *(const float4*)&Ar[4];
            float4 q2 = *(const float4*)&Ar[8];
            float4 q3 = *(const float4*)&Ar[12];
            float rA[16] = {q0.x,q0.y,q0.z,q0.w, q1.x,q1.y,q1.z,q1.w,
                            q2.x,q2.y,q2.z,q2.w, q3.x,q3.y,q3.z,q3.w};
            float lo[16];
#pragma unroll
            for (int t = 0; t < 16; ++t) lo[t] = 0.f;
#pragma unroll
            for (int a = 0; a < 16; ++a) {
                float va = rA[a];
                const float* Trow = &Amat[(base + a) * PITCH + base];  // T[t,a], t contiguous
                float4 t0 = *(const float4*)&Trow[0];
                float4 t1 = *(const float4*)&Trow[4];
                float4 t2 = *(const float4*)&Trow[8];
                float4 t3 = *(const float4*)&Trow[12];
                lo[0] += va * t0.x; lo[1] += va * t0.y; lo[2] += va * t0.z; lo[3] += va * t0.w;
                lo[4] += va * t1.x; lo[5] += va * t1.y; lo[6] += va * t1.z; lo[7] += va * t1.w;
                lo[8] += va * t2.x; lo[9] += va * t2.y; lo[10] += va * t2.z; lo[11] += va * t2.w;
                lo[12] += va * t3.x; lo[13] += va * t3.y; lo[14] += va * t3.z; lo[15] += va * t3.w;
            }
            float* Aw = &Amat[i * PITCH + base];
            *(float4*)&Aw[0]  = make_float4(lo[0], lo[1], lo[2], lo[3]);
            *(float4*)&Aw[4]  = make_float4(lo[4], lo[5], lo[6], lo[7]);
            *(float4*)&Aw[8]  = make_float4(lo[8], lo[9], lo[10], lo[11]);
            *(float4*)&Aw[12] = make_float4(lo[12], lo[13], lo[14], lo[15]);
#pragma unroll
            for (int t = 0; t < 16; ++t) Wb[t * PITCH + i] = lo[t];
        }
        __syncthreads();
        if (R > 0) {
            // rhs below-update: z[i] -= L[i,panel] . z'
            if (tid >= base + 16 && tid < 128) {
                int i = tid;
                const float* Lr = &Amat[i * PITCH + base];
                float dv = 0.f, dd2 = 0.f;
#pragma unroll
                for (int t = 0; t < 16; ++t) {
                    float lv = Lr[t];
                    dv  += lv * zv[base + t];
                    dd2 += lv * zd[base + t];
                }
                zv[i] -= dv; zd[i] -= dd2;
            }
            // rank-16 Schur on trailing square, 8x8 register tiles from W rows
            int nt = R >> 3;
            for (int tau = tid; tau < nt * nt; tau += 256) {
                int tr = tau / nt, tc = tau - tr * nt;
                int ii = base + 16 + tr * 8, jj = base + 16 + tc * 8;
                float a2[8][8];
#pragma unroll
                for (int r = 0; r < 8; ++r)
#pragma unroll
                    for (int c = 0; c < 8; ++c) a2[r][c] = 0.f;
#pragma unroll
                for (int t = 0; t < 16; ++t) {
                    const float* wr = &Wb[t * PITCH];
                    float4 x0 = *(const float4*)&wr[ii];
                    float4 x1 = *(const float4*)&wr[ii + 4];
                    float4 y0 = *(const float4*)&wr[jj];
                    float4 y1 = *(const float4*)&wr[jj + 4];
                    float xa[8] = {x0.x,x0.y,x0.z,x0.w, x1.x,x1.y,x1.z,x1.w};
                    float yb[8] = {y0.x,y0.y,y0.z,y0.w, y1.x,y1.y,y1.z,y1.w};
#pragma unroll
                    for (int r = 0; r < 8; ++r)
#pragma unroll
                        for (int c = 0; c < 8; ++c) a2[r][c] += xa[r] * yb[c];
                }
#pragma unroll
                for (int r = 0; r < 8; ++r) {
                    float* Ar2 = &Amat[(ii + r) * PITCH + jj];
                    float4 u0 = *(float4*)&Ar2[0];
                    float4 u1 = *(float4*)&Ar2[4];
                    u0.x -= a2[r][0]; u0.y -= a2[r][1]; u0.z -= a2[r][2]; u0.w -= a2[r][3];
                    u1.x -= a2[r][4]; u1.y -= a2[r][5]; u1.z -= a2[r][6]; u1.w -= a2[r][7];
                    *(float4*)&Ar2[0] = u0;
                    *(float4*)&Ar2[4] = u1;
                }
            }
        }
    }
    // ---- phase 3b: X = L^{-1} via 7 diagonal block-sweeps; X^T stored in upper triangle
    for (int s = 1; s <= 7; ++s) {
        __syncthreads();
        int npair = 8 - s;
        for (int idx = tid; idx < npair * 256; idx += 256) {
            int pr = idx >> 8;
            int J = pr, i = pr + s;
            int a = (idx >> 4) & 15, bb = idx & 15;
            const float* u = &Amat[(16 * i + a) * PITCH + 16 * J];
            const float* w = &Amat[(16 * J + bb) * PITCH + 16 * J];
            int len = 16 * s;
            float sacc = 0.f;
            for (int k2 = 0; k2 < len; k2 += 4) {
                float4 uu = *(const float4*)&u[k2];
                float4 ww = *(const float4*)&w[k2];
                sacc += uu.x * ww.x + uu.y * ww.y + uu.z * ww.z + uu.w * ww.w;
            }
            Sbuf[pr * 256 + a * 16 + bb] = sacc;
        }
        __syncthreads();
        for (int idx = tid; idx < npair * 256; idx += 256) {
            int pr = idx >> 8;
            int J = pr, i = pr + s;
            int cc = (idx >> 4) & 15, bb = idx & 15;
            float a0 = 0.f;
#pragma unroll
            for (int a = 0; a < 16; ++a)
                a0 += Amat[(16 * i + a) * PITCH + 16 * i + cc] * Sbuf[pr * 256 + a * 16 + bb];
            Amat[(16 * J + bb) * PITCH + 16 * i + cc] = -a0;
        }
    }
    __syncthreads();
    // ---- phase 4: trinv = ||L^{-1}||_F^2 (upper-incl-diag-block region), qv, qd
    float p_ti = 0.f, p_qv = 0.f, p_qd = 0.f;
    {
        int i = tid & 127, h = tid >> 7;
        int c0 = (i >> 4) << 4;
        int half = (128 - c0) >> 1;      // multiple of 8
        const float* Ar = &Amat[i * PITCH + c0 + h * half];
        for (int k2 = 0; k2 < half; k2 += 4) {
            float4 a = *(const float4*)&Ar[k2];
            p_ti += a.x * a.x + a.y * a.y + a.z * a.z + a.w * a.w;
        }
    }
    if (tid < 128) {
        float a = zv[tid];  p_qv = a * a;
        float d2 = zd[tid]; p_qd = d2 * d2;
    }
    float trinv = bsum(p_ti, red);
    float qv = bsum(p_qv, red);
    float qd = bsum(p_qd, red);
    if (tid == 0) {
        float n = 1.f + nv;
        float Aterm = trP - vsv / n;          // tr(Sq^{-1} Sp)
        float Bt = trinv + qv;                // tr(Sp^{-1} Sq)
        float mq = dds - vds * vds / n;       // delta^T Sq^{-1} delta
        outR[bid] = 0.25f * (Aterm + Bt - 256.f + mq + qd);
    }
}

// ---------------------------------------------------------------- K5: broadcast outputs lm_b, lc_b
__global__ __launch_bounds__(256)
void k5_bcast(const float* __restrict__ lmg, const float* __restrict__ ldvg,
              float* __restrict__ out) {
    const int TOT = 16384 + 2097152;
    float4* outLM = (float4*)(out + 512);
    float4* outLC = (float4*)(out + 512 + 65536);
    for (int idx = blockIdx.x * 256 + threadIdx.x; idx < TOT; idx += gridDim.x * 256) {
        if (idx < 16384) {
            int flat = idx * 4;
            int d0 = flat & 127;
            int l = (flat >> 7) & 63;
            outLM[idx] = *(const float4*)&lmg[l * 128 + d0];
        } else {
            int g = idx - 16384;
            int flat = g * 4;
            int j0v = flat & 127;
            int i = (flat >> 7) & 127;
            int l = (flat >> 14) & 63;
            float vi = ldvg[l * 128 + i];
            float4 vj = *(const float4*)&ldvg[l * 128 + j0v];
            float4 r;
            r.x = vi * vj.x + ((i == j0v + 0) ? 1.f : 0.f);
            r.y = vi * vj.y + ((i == j0v + 1) ? 1.f : 0.f);
            r.z = vi * vj.z + ((i == j0v + 2) ? 1.f : 0.f);
            r.w = vi * vj.w + ((i == j0v + 3) ? 1.f : 0.f);
            outLC[g] = r;
        }
    }
}

// ---------------------------------------------------------------- launch
extern "C" void kernel_launch(void* const* d_in, const int* in_sizes, int n_in,
                              void* d_out, int out_size, void* d_ws, size_t ws_size,
                              hipStream_t stream) {
    const float* wfm = (const float*)d_in[0];
    const float* wfd = (const float*)d_in[1];
    const float* sfm = (const float*)d_in[2];
    const float* sfd = (const float*)d_in[3];
    const float* W1 = (const float*)d_in[4];
    const float* B1 = (const float*)d_in[5];
    const float* W2 = (const float*)d_in[6];
    const float* B2 = (const float*)d_in[7];
    const float* W3 = (const float*)d_in[8];
    const float* B3 = (const float*)d_in[9];
    const float* W4 = (const float*)d_in[10];
    const float* B4 = (const float*)d_in[11];
    const float* lm = (const float*)d_in[12];
    const float* ldv = (const float*)d_in[13];
    float* out = (float*)d_out;
    float* ws = (float*)d_ws;

    float* wm = ws;                         // 262144
    float* wv = ws + 262144;                // 262144
    float* sm = ws + 524288;                // 1024
    float* sv = ws + 525312;                // 1024
    float4* rowsc = (float4*)(ws + 526336); // 2048 float4
    float4* labsc = (float4*)(ws + 534528); // 64 float4
    float* score = ws + 534784;             // 131072

    constexpr int SH_FLOATS = 19408;
    constexpr size_t SH_BYTES = SH_FLOATS * sizeof(float);   // 77632 B -> 2 blocks/CU
    (void)hipFuncSetAttribute((const void*)k4_main,
                              hipFuncAttributeMaxDynamicSharedMemorySize,
                              (int)SH_BYTES);

    k5_bcast<<<2048, 256, 0, stream>>>(lm, ldv, out);
    k1_gemm<<<dim3(128, 2), 256, 0, stream>>>(wfm, wfd, W1, B1, W2, B2, wm, wv);
    k1b_sent<<<8, 128, 0, stream>>>(sfm, sfd, W3, B3, W4, B4, sm, sv);
    k2a_scal<<<528, 256, 0, stream>>>(wm, wv, lm, ldv, rowsc, labsc);
    k2b_score<<<512, 256, 0, stream>>>(wm, wv, lm, ldv, rowsc, labsc, score);
    k4_main<<<512, 256, SH_BYTES, stream>>>(wm, wv, sm, sv, lm, ldv, score, out);
}